// Round 6
// baseline (1375.665 us; speedup 1.0000x reference)
//
#include <hip/hip_runtime.h>
#include <hip/hip_bf16.h>

#define LN_EPS 1e-5f

typedef __attribute__((ext_vector_type(8))) short bf16x8;
typedef __attribute__((ext_vector_type(4))) float f32x4;

static __device__ __forceinline__ unsigned short f2bf(float x) {
    unsigned int u = __float_as_uint(x);
    return (unsigned short)((u + 0x7FFFu + ((u >> 16) & 1u)) >> 16);
}
static __device__ __forceinline__ float bf2f(unsigned short u) {
    return __uint_as_float(((unsigned int)u) << 16);
}
static __device__ __forceinline__ uint2 pack4bf(float a, float b, float c, float d) {
    uint2 r;
    r.x = (unsigned int)f2bf(a) | ((unsigned int)f2bf(b) << 16);
    r.y = (unsigned int)f2bf(c) | ((unsigned int)f2bf(d) << 16);
    return r;
}

// ---------------------------------------------------------------------------
// Weight packers: fragment-ready layout for mfma_f32_16x16x32_bf16 A-operand.
// Tile (kb, nt), lane l: m = nt*16 + (l&15), k = kb*32 + (l>>4)*8 + i (16B run).
// ---------------------------------------------------------------------------
__global__ void pack_w_kernel(const float* __restrict__ Wk, const float* __restrict__ Wv,
                              unsigned short* __restrict__ Bp, int KB, int Kreal)
{
    int idx = blockIdx.x * 256 + threadIdx.x;
    if (idx >= KB * 1024) return;
    int kb = idx >> 10, rem = idx & 1023, nt = rem >> 6, l = rem & 63;
    int n_g = nt * 16 + (l & 15);
    int kbase = kb * 32 + ((l >> 4) * 8);
    const float* W = (n_g < 128) ? Wk : Wv;
    int n = (n_g < 128) ? n_g : n_g - 128;
    unsigned short o[8];
    #pragma unroll
    for (int i = 0; i < 8; ++i) {
        int k = kbase + i;
        o[i] = (k < Kreal) ? f2bf(W[(size_t)k * 128 + n]) : (unsigned short)0;
    }
    *(int4*)(Bp + (size_t)idx * 8) = *(const int4*)o;
}

__global__ void pack_w128_kernel(const float* __restrict__ W,
                                 unsigned short* __restrict__ Bp, int KB, int Kreal)
{
    int idx = blockIdx.x * 256 + threadIdx.x;
    if (idx >= KB * 512) return;
    int kb = idx >> 9, rem = idx & 511, nt = rem >> 6, l = rem & 63;
    int n = nt * 16 + (l & 15);
    int kbase = kb * 32 + ((l >> 4) * 8);
    unsigned short o[8];
    #pragma unroll
    for (int i = 0; i < 8; ++i) {
        int k = kbase + i;
        o[i] = (k < Kreal) ? f2bf(W[(size_t)k * 128 + n]) : (unsigned short)0;
    }
    *(int4*)(Bp + (size_t)idx * 8) = *(const int4*)o;
}

__global__ void f32_to_bf16_kernel(const float* __restrict__ in,
                                   unsigned short* __restrict__ out, long n8)
{
    long i = (long)blockIdx.x * 256 + threadIdx.x;
    if (i >= n8) return;
    const float4* p = (const float4*)(in + i * 8);
    float4 a = p[0], b = p[1];
    unsigned short o[8] = { f2bf(a.x), f2bf(a.y), f2bf(a.z), f2bf(a.w),
                            f2bf(b.x), f2bf(b.y), f2bf(b.z), f2bf(b.w) };
    *(int4*)(out + i * 8) = *(const int4*)o;
}

// ---------------------------------------------------------------------------
// Node-side MFMA MLP: out = ReLU(LN(x @ W1 + b1)) @ W2 + b2, 128 rows/block.
// DIN=128: x = in_bf (bf16). DIN=256: x = [in_f (fp32) | in_bf], two K-passes
// through one a1[128][136] buffer (LDS < 64 KB limit). If den != null, the
// fp32 half is normalized per-head: x[col] *= (den[row][col>>3] > 0 ?
// 1/den[...] : 0)  — deferred softmax normalization of the attn accumulator.
// ---------------------------------------------------------------------------
template<int DIN, typename OUT>
__global__ __launch_bounds__(256, 2) void node_mlp_mfma_kernel(
    const unsigned short* __restrict__ in_bf, const float* __restrict__ in_f,
    const float* __restrict__ den,
    const unsigned short* __restrict__ W1p, const unsigned short* __restrict__ W2p,
    const float* __restrict__ b1, const float* __restrict__ g,
    const float* __restrict__ be, const float* __restrict__ b2,
    OUT* __restrict__ out, int nrows)
{
    constexpr int NPASS = DIN / 128;
    struct Smem {
        union __align__(16) {
            unsigned short a1[128][136];
            unsigned short a2[128][136];
        } u;
        float2 gbuf[128];
        float  b1buf[128], b2buf[128];
        float2 lnred[4][64];
        float2 lnstat[128];
    };
    __shared__ Smem sm;

    const int tid = threadIdx.x;
    const int w = tid >> 6, l = tid & 63, lg = l >> 4, li = l & 15;
    const int rt = w >> 1, ct = w & 1;
    const long r0 = (long)blockIdx.x * 128;

    if (tid < 128) {
        sm.gbuf[tid]  = make_float2(g[tid], be[tid]);
        sm.b1buf[tid] = b1[tid];
        sm.b2buf[tid] = b2[tid];
    }

    const int se = tid >> 1, sp = tid & 1;
    long srg = r0 + se; if (srg >= nrows) srg = nrows - 1;

    f32x4 acc[4][4];
    #pragma unroll
    for (int mt = 0; mt < 4; ++mt)
        #pragma unroll
        for (int et = 0; et < 4; ++et)
            acc[mt][et] = (f32x4){0.f, 0.f, 0.f, 0.f};

    // ---- layer 1: NPASS K-chunks of 128 through the shared a1 buffer
    #pragma unroll
    for (int pass = 0; pass < NPASS; ++pass) {
        if constexpr (NPASS == 2) {
            if (pass == 0) {
                // fp32 attn half, normalized by den (softmax denominator)
                float inv[8];
                const float4* dp = (const float4*)(den + (size_t)srg * 16 + sp * 8);
                float4 d0 = dp[0], d1 = dp[1];
                inv[0] = d0.x > 0.f ? 1.f / d0.x : 0.f;
                inv[1] = d0.y > 0.f ? 1.f / d0.y : 0.f;
                inv[2] = d0.z > 0.f ? 1.f / d0.z : 0.f;
                inv[3] = d0.w > 0.f ? 1.f / d0.w : 0.f;
                inv[4] = d1.x > 0.f ? 1.f / d1.x : 0.f;
                inv[5] = d1.y > 0.f ? 1.f / d1.y : 0.f;
                inv[6] = d1.z > 0.f ? 1.f / d1.z : 0.f;
                inv[7] = d1.w > 0.f ? 1.f / d1.w : 0.f;
                const float4* af = (const float4*)(in_f + (size_t)srg * 128 + sp * 64);
                #pragma unroll
                for (int i = 0; i < 16; ++i) {
                    float4 v = af[i];
                    float iv = inv[i >> 1];
                    *(uint2*)&sm.u.a1[se][sp * 64 + i * 4] =
                        pack4bf(v.x * iv, v.y * iv, v.z * iv, v.w * iv);
                }
            } else {
                const int4* s = (const int4*)(in_bf + (size_t)srg * 128 + sp * 64);
                int4* d = (int4*)&sm.u.a1[se][sp * 64];
                #pragma unroll
                for (int i = 0; i < 8; ++i) d[i] = s[i];   // 8 int4 = 64 bf16
            }
        } else {
            const int4* s = (const int4*)(in_bf + (size_t)srg * 128 + sp * 64);
            int4* d = (int4*)&sm.u.a1[se][sp * 64];
            #pragma unroll
            for (int i = 0; i < 8; ++i) d[i] = s[i];       // 8 int4 = 64 bf16
        }
        __syncthreads();

        #pragma unroll
        for (int kb = 0; kb < 4; ++kb) {
            bf16x8 wf[4], bfr[4];
            #pragma unroll
            for (int mt = 0; mt < 4; ++mt)
                wf[mt] = *(const bf16x8*)(W1p +
                    ((size_t)((pass * 4 + kb) * 8 + ct * 4 + mt) * 512 + l * 8));
            #pragma unroll
            for (int et = 0; et < 4; ++et)
                bfr[et] = *(const bf16x8*)(&sm.u.a1[rt * 64 + et * 16 + li][kb * 32 + lg * 8]);
            #pragma unroll
            for (int mt = 0; mt < 4; ++mt)
                #pragma unroll
                for (int et = 0; et < 4; ++et)
                    acc[mt][et] = __builtin_amdgcn_mfma_f32_16x16x32_bf16(
                        wf[mt], bfr[et], acc[mt][et], 0, 0, 0);
        }
        __syncthreads();   // a1 reads complete before restage / a2 overwrite
    }

    // ---- + b1, LN partials over this wave's 64 cols
    #pragma unroll
    for (int mt = 0; mt < 4; ++mt)
        #pragma unroll
        for (int r = 0; r < 4; ++r) {
            float b1v = sm.b1buf[ct * 64 + mt * 16 + lg * 4 + r];
            #pragma unroll
            for (int et = 0; et < 4; ++et) acc[mt][et][r] += b1v;
        }
    #pragma unroll
    for (int et = 0; et < 4; ++et) {
        float s = 0.f, sq = 0.f;
        #pragma unroll
        for (int mt = 0; mt < 4; ++mt)
            #pragma unroll
            for (int r = 0; r < 4; ++r) {
                float x = acc[mt][et][r];
                s += x; sq += x * x;
            }
        s  += __shfl_xor(s, 16, 64);  sq += __shfl_xor(sq, 16, 64);
        s  += __shfl_xor(s, 32, 64);  sq += __shfl_xor(sq, 32, 64);
        if (lg == 0) sm.lnred[w][et * 16 + li] = make_float2(s, sq);
    }
    __syncthreads();
    if (tid < 128) {
        int row = tid, rr = row >> 6;
        float2 p0 = sm.lnred[rr * 2][row & 63], p1 = sm.lnred[rr * 2 + 1][row & 63];
        float mu  = (p0.x + p1.x) * (1.f / 128.f);
        float var = (p0.y + p1.y) * (1.f / 128.f) - mu * mu;
        sm.lnstat[row] = make_float2(mu, rsqrtf(var + LN_EPS));
    }
    __syncthreads();

    // ---- normalize + ReLU -> a2 (bf16)
    {
        float2 stat[4];
        #pragma unroll
        for (int et = 0; et < 4; ++et) stat[et] = sm.lnstat[rt * 64 + et * 16 + li];
        #pragma unroll
        for (int mt = 0; mt < 4; ++mt) {
            float2 gb[4];
            #pragma unroll
            for (int r = 0; r < 4; ++r) gb[r] = sm.gbuf[ct * 64 + mt * 16 + lg * 4 + r];
            #pragma unroll
            for (int et = 0; et < 4; ++et) {
                float x0 = fmaxf(fmaf((acc[mt][et][0] - stat[et].x) * stat[et].y, gb[0].x, gb[0].y), 0.f);
                float x1 = fmaxf(fmaf((acc[mt][et][1] - stat[et].x) * stat[et].y, gb[1].x, gb[1].y), 0.f);
                float x2 = fmaxf(fmaf((acc[mt][et][2] - stat[et].x) * stat[et].y, gb[2].x, gb[2].y), 0.f);
                float x3 = fmaxf(fmaf((acc[mt][et][3] - stat[et].x) * stat[et].y, gb[3].x, gb[3].y), 0.f);
                *(uint2*)&sm.u.a2[rt * 64 + et * 16 + li][ct * 64 + mt * 16 + lg * 4] =
                    pack4bf(x0, x1, x2, x3);
            }
        }
    }
    __syncthreads();

    // ---- layer 2
    #pragma unroll
    for (int mt = 0; mt < 4; ++mt)
        #pragma unroll
        for (int et = 0; et < 4; ++et)
            acc[mt][et] = (f32x4){0.f, 0.f, 0.f, 0.f};

    for (int kb = 0; kb < 4; ++kb) {
        bf16x8 wf[4], bfr[4];
        #pragma unroll
        for (int mt = 0; mt < 4; ++mt)
            wf[mt] = *(const bf16x8*)(W2p + ((size_t)(kb * 8 + ct * 4 + mt) * 512 + l * 8));
        #pragma unroll
        for (int et = 0; et < 4; ++et)
            bfr[et] = *(const bf16x8*)(&sm.u.a2[rt * 64 + et * 16 + li][kb * 32 + lg * 8]);
        #pragma unroll
        for (int mt = 0; mt < 4; ++mt)
            #pragma unroll
            for (int et = 0; et < 4; ++et)
                acc[mt][et] = __builtin_amdgcn_mfma_f32_16x16x32_bf16(
                    wf[mt], bfr[et], acc[mt][et], 0, 0, 0);
    }

    // ---- epilogue: + b2, store
    float b2v[4][4];
    #pragma unroll
    for (int mt = 0; mt < 4; ++mt)
        #pragma unroll
        for (int r = 0; r < 4; ++r)
            b2v[mt][r] = sm.b2buf[ct * 64 + mt * 16 + lg * 4 + r];
    #pragma unroll
    for (int et = 0; et < 4; ++et) {
        long rg = r0 + rt * 64 + et * 16 + li;
        if (rg < nrows) {
            #pragma unroll
            for (int mt = 0; mt < 4; ++mt) {
                float y0 = acc[mt][et][0] + b2v[mt][0];
                float y1 = acc[mt][et][1] + b2v[mt][1];
                float y2 = acc[mt][et][2] + b2v[mt][2];
                float y3 = acc[mt][et][3] + b2v[mt][3];
                size_t o = (size_t)rg * 128 + ct * 64 + mt * 16 + lg * 4;
                if constexpr (sizeof(OUT) == 2) {
                    *(uint2*)(out + o) = pack4bf(y0, y1, y2, y3);
                } else {
                    float4 v = make_float4(y0, y1, y2, y3);
                    *(float4*)((float*)out + o) = v;
                }
            }
        }
    }
}

// ---------------------------------------------------------------------------
// MFMA edge kernel: 64 edges/block, fused xk|xv MLPs (256 output cols),
// LN+ReLU between layers. Epilogue: scores (k fp32 LDS · q gathered from
// global) -> exp -> den atomics -> FUSED scatter: attn[dst] += ex*e_w*v
// straight from the v-half accumulators (no v/ex materialization, no agg
// pass; normalization is deferred to the out-MLP staging).
// ---------------------------------------------------------------------------
__global__ __launch_bounds__(256, 3) void kv_mfma_kernel(
    const unsigned short* __restrict__ h_bf,   // [N][128] bf16
    const unsigned short* __restrict__ q_bf,   // [N][128] bf16
    const float* __restrict__ r_feat, const float* __restrict__ edge_feat,
    const float* __restrict__ e_w,
    const int* __restrict__ src_idx, const int* __restrict__ dst_idx,
    const unsigned short* __restrict__ B1p, const unsigned short* __restrict__ B2p,
    const float* __restrict__ kb1, const float* __restrict__ vb1,
    const float* __restrict__ kg,  const float* __restrict__ kbeta,
    const float* __restrict__ vg,  const float* __restrict__ vbeta,
    const float* __restrict__ kb2, const float* __restrict__ vb2,
    float* __restrict__ attn, float* __restrict__ den, int E)
{
    struct Smem {
        union __align__(16) {
            unsigned short a1[64][296];   // layer-1 input bf16 (280 + pad)
            unsigned short a2[64][264];   // layer-2 input bf16 (256 + pad)
            float          kbuf[64][132]; // k output fp32 (128 + pad)
        } u;                              // 37,888 B (~48.8 KB total -> 3 blk/CU)
        float  sex[64][17];               // exp(score) per edge x head (+pad)
        float2 gbuf[256];
        float  b1buf[256], b2buf[256];
        float2 lnred[4][64];
        float2 lnstat[2][64];
        int    sdst[64];
        float  sew[64];
    };
    __shared__ Smem sm;

    const int tid = threadIdx.x;
    const int w  = tid >> 6, l = tid & 63, lg = l >> 4, li = l & 15;
    const long e0 = (long)blockIdx.x * 64;

    {
        int c = tid;
        float g  = (c < 128) ? kg[c]    : vg[c - 128];
        float be = (c < 128) ? kbeta[c] : vbeta[c - 128];
        sm.gbuf[c]  = make_float2(g, be);
        sm.b1buf[c] = (c < 128) ? kb1[c] : vb1[c - 128];
        sm.b2buf[c] = (c < 128) ? kb2[c] : vb2[c - 128];
    }
    {
        int e = tid >> 2, qt = tid & 3;
        long eg = e0 + e; if (eg >= E) eg = E - 1;
        int d = dst_idx[eg], s = src_idx[eg];
        const int4* hd = (const int4*)(h_bf + (size_t)d * 128 + qt * 32);
        const int4* hs = (const int4*)(h_bf + (size_t)s * 128 + qt * 32);
        int4* a1d = (int4*)&sm.u.a1[e][24  + qt * 32];
        int4* a1s = (int4*)&sm.u.a1[e][152 + qt * 32];
        #pragma unroll
        for (int i = 0; i < 4; ++i) { a1d[i] = hd[i]; a1s[i] = hs[i]; }
        if (qt == 0) {
            float4 ef = *(const float4*)(edge_feat + (size_t)eg * 4);
            *(uint2*)&sm.u.a1[e][0] = pack4bf(ef.x, ef.y, ef.z, ef.w);
            const float4* rf = (const float4*)(r_feat + (size_t)eg * 20);
            #pragma unroll
            for (int i = 0; i < 5; ++i) {
                float4 v = rf[i];
                *(uint2*)&sm.u.a1[e][4 + i * 4] = pack4bf(v.x, v.y, v.z, v.w);
            }
            int4 z = {0,0,0,0};
            *(int4*)&sm.u.a1[e][280] = z;
            *(int4*)&sm.u.a1[e][288] = z;
        } else if (qt == 1) {
            sm.sdst[e] = d;
            sm.sew[e]  = e_w[eg];
        }
    }
    __syncthreads();

    f32x4 acc[4][4];
    #pragma unroll
    for (int mt = 0; mt < 4; ++mt)
        #pragma unroll
        for (int et = 0; et < 4; ++et)
            acc[mt][et] = (f32x4){0.f, 0.f, 0.f, 0.f};

    for (int kb = 0; kb < 9; ++kb) {
        bf16x8 wf[4], bfr[4];
        #pragma unroll
        for (int mt = 0; mt < 4; ++mt)
            wf[mt] = *(const bf16x8*)(B1p + ((size_t)(kb * 16 + w * 4 + mt) * 512 + l * 8));
        #pragma unroll
        for (int et = 0; et < 4; ++et)
            bfr[et] = *(const bf16x8*)(&sm.u.a1[et * 16 + li][kb * 32 + lg * 8]);
        #pragma unroll
        for (int mt = 0; mt < 4; ++mt)
            #pragma unroll
            for (int et = 0; et < 4; ++et)
                acc[mt][et] = __builtin_amdgcn_mfma_f32_16x16x32_bf16(
                    wf[mt], bfr[et], acc[mt][et], 0, 0, 0);
    }

    #pragma unroll
    for (int mt = 0; mt < 4; ++mt)
        #pragma unroll
        for (int r = 0; r < 4; ++r) {
            float b1v = sm.b1buf[w * 64 + mt * 16 + lg * 4 + r];
            #pragma unroll
            for (int et = 0; et < 4; ++et) acc[mt][et][r] += b1v;
        }

    {
        #pragma unroll
        for (int et = 0; et < 4; ++et) {
            float s = 0.f, sq = 0.f;
            #pragma unroll
            for (int mt = 0; mt < 4; ++mt)
                #pragma unroll
                for (int r = 0; r < 4; ++r) {
                    float x = acc[mt][et][r];
                    s += x; sq += x * x;
                }
            s  += __shfl_xor(s, 16, 64);  sq += __shfl_xor(sq, 16, 64);
            s  += __shfl_xor(s, 32, 64);  sq += __shfl_xor(sq, 32, 64);
            if (lg == 0) sm.lnred[w][et * 16 + li] = make_float2(s, sq);
        }
    }
    __syncthreads();
    if (tid < 128) {
        int half = tid >> 6, e = tid & 63;
        float2 p0 = sm.lnred[half * 2][e], p1 = sm.lnred[half * 2 + 1][e];
        float mu  = (p0.x + p1.x) * (1.f / 128.f);
        float var = (p0.y + p1.y) * (1.f / 128.f) - mu * mu;
        sm.lnstat[half][e] = make_float2(mu, rsqrtf(var + LN_EPS));
    }
    __syncthreads();

    {
        float2 stat[4];
        #pragma unroll
        for (int et = 0; et < 4; ++et) stat[et] = sm.lnstat[w >> 1][et * 16 + li];
        #pragma unroll
        for (int mt = 0; mt < 4; ++mt) {
            float2 gb[4];
            #pragma unroll
            for (int r = 0; r < 4; ++r) gb[r] = sm.gbuf[w * 64 + mt * 16 + lg * 4 + r];
            #pragma unroll
            for (int et = 0; et < 4; ++et) {
                float x0 = fmaxf(fmaf((acc[mt][et][0] - stat[et].x) * stat[et].y, gb[0].x, gb[0].y), 0.f);
                float x1 = fmaxf(fmaf((acc[mt][et][1] - stat[et].x) * stat[et].y, gb[1].x, gb[1].y), 0.f);
                float x2 = fmaxf(fmaf((acc[mt][et][2] - stat[et].x) * stat[et].y, gb[2].x, gb[2].y), 0.f);
                float x3 = fmaxf(fmaf((acc[mt][et][3] - stat[et].x) * stat[et].y, gb[3].x, gb[3].y), 0.f);
                *(uint2*)&sm.u.a2[et * 16 + li][w * 64 + mt * 16 + lg * 4] = pack4bf(x0, x1, x2, x3);
            }
        }
    }
    __syncthreads();

    #pragma unroll
    for (int mt = 0; mt < 4; ++mt)
        #pragma unroll
        for (int et = 0; et < 4; ++et)
            acc[mt][et] = (f32x4){0.f, 0.f, 0.f, 0.f};

    const int koff = (w < 2) ? 0 : 128;
    for (int kb = 0; kb < 4; ++kb) {
        bf16x8 wf[4], bfr[4];
        #pragma unroll
        for (int mt = 0; mt < 4; ++mt)
            wf[mt] = *(const bf16x8*)(B2p + ((size_t)(kb * 16 + w * 4 + mt) * 512 + l * 8));
        #pragma unroll
        for (int et = 0; et < 4; ++et)
            bfr[et] = *(const bf16x8*)(&sm.u.a2[et * 16 + li][koff + kb * 32 + lg * 8]);
        #pragma unroll
        for (int mt = 0; mt < 4; ++mt)
            #pragma unroll
            for (int et = 0; et < 4; ++et)
                acc[mt][et] = __builtin_amdgcn_mfma_f32_16x16x32_bf16(
                    wf[mt], bfr[et], acc[mt][et], 0, 0, 0);
    }
    #pragma unroll
    for (int mt = 0; mt < 4; ++mt)
        #pragma unroll
        for (int r = 0; r < 4; ++r) {
            float b2v = sm.b2buf[w * 64 + mt * 16 + lg * 4 + r];
            #pragma unroll
            for (int et = 0; et < 4; ++et) acc[mt][et][r] += b2v;
        }
    __syncthreads();   // all a2 reads done before kbuf overwrites the union

    // ---- waves 0,1 stash k (fp32) to LDS; waves 2,3 keep v in registers
    if (w < 2) {
        #pragma unroll
        for (int mt = 0; mt < 4; ++mt)
            #pragma unroll
            for (int et = 0; et < 4; ++et)
                *(f32x4*)&sm.u.kbuf[et * 16 + li][w * 64 + mt * 16 + lg * 4] = acc[mt][et];
    }
    __syncthreads();

    // ---- scores: 64 edges x 16 heads; q gathered from global (L2-resident)
    {
        int e = tid >> 2, hb = (tid & 3) * 4;
        long eg = e0 + e;
        int d = sm.sdst[e];
        const int4* qp = (const int4*)(q_bf + (size_t)d * 128 + hb * 8);
        int4 q4[4];
        #pragma unroll
        for (int i = 0; i < 4; ++i) q4[i] = qp[i];
        if (eg < E) {
            #pragma unroll
            for (int hh = 0; hh < 4; ++hh) {
                const float* kr = &sm.u.kbuf[e][(hb + hh) * 8];
                const unsigned short* qq = (const unsigned short*)&q4[hh];
                float sc = 0.f;
                #pragma unroll
                for (int t = 0; t < 8; ++t) sc = fmaf(kr[t], bf2f(qq[t]), sc);
                sc *= 0.35355339059327373f;   // 1/sqrt(8)
                float exv = __expf(sc);
                sm.sex[e][hb + hh] = exv;
                unsafeAtomicAdd(&den[(size_t)d * 16 + hb + hh], exv);
            }
        }
    }
    __syncthreads();   // sex ready

    // ---- fused scatter: attn[dst] += ex * e_w * v  (v-half accumulators)
    if (w >= 2) {
        #pragma unroll
        for (int et = 0; et < 4; ++et) {
            int e = et * 16 + li;
            long eg = e0 + e;
            if (eg < E) {
                int d = sm.sdst[e];
                float ew = sm.sew[e];
                float* arow = attn + (size_t)d * 128 + (w - 2) * 64;
                #pragma unroll
                for (int mt = 0; mt < 4; ++mt) {
                    int cbase = mt * 16 + lg * 4;
                    float scale = ew * sm.sex[e][((w - 2) * 64 + cbase) >> 3];
                    #pragma unroll
                    for (int r = 0; r < 4; ++r)
                        unsafeAtomicAdd(&arow[cbase + r], acc[mt][et][r] * scale);
                }
            }
        }
    }
}

// ---------------------------------------------------------------------------
extern "C" void kernel_launch(void* const* d_in, const int* in_sizes, int n_in,
                              void* d_out, int out_size, void* d_ws, size_t ws_size,
                              hipStream_t stream)
{
    const float* h         = (const float*)d_in[0];
    const float* r_feat    = (const float*)d_in[1];
    const float* edge_feat = (const float*)d_in[2];
    const int*   edge_idx  = (const int*)d_in[3];
    const float* e_w       = (const float*)d_in[4];
    const float* P[24];
    for (int i = 0; i < 24; ++i) P[i] = (const float*)d_in[5 + i];
    // P[0..5]=xk{W1,b1,g,beta,W2,b2}  P[6..11]=xv  P[12..17]=xq  P[18..23]=out

    const int N = in_sizes[0] / 128;
    const int E = in_sizes[4];
    const int* src = edge_idx;
    const int* dst = edge_idx + E;

    // workspace carve: h_bf | q_bf | B1p | B2p | W1q | W2q | W1o | W2o | attn | den
    char* p = (char*)d_ws;
    unsigned short* h_bf = (unsigned short*)p; p += (size_t)N * 128 * 2;
    unsigned short* q_bf = (unsigned short*)p; p += (size_t)N * 128 * 2;
    unsigned short* B1p  = (unsigned short*)p; p += (size_t)9 * 16 * 512 * 2;
    unsigned short* B2p  = (unsigned short*)p; p += (size_t)4 * 16 * 512 * 2;
    unsigned short* W1q  = (unsigned short*)p; p += (size_t)4 * 8 * 512 * 2;
    unsigned short* W2q  = (unsigned short*)p; p += (size_t)4 * 8 * 512 * 2;
    unsigned short* W1o  = (unsigned short*)p; p += (size_t)8 * 8 * 512 * 2;
    unsigned short* W2o  = (unsigned short*)p; p += (size_t)4 * 8 * 512 * 2;
    float* attn          = (float*)p;          p += (size_t)N * 128 * 4;
    float* den           = (float*)p;          p += (size_t)N * 16 * 4;

    // zero attn + den (adjacent)
    hipMemsetAsync(attn, 0, (size_t)N * 144 * sizeof(float), stream);

    // prep: h -> bf16; pack all weights
    f32_to_bf16_kernel<<<dim3((N * 128 / 8 + 255) / 256), dim3(256), 0, stream>>>(
        h, h_bf, (long)N * 128 / 8);
    pack_w_kernel<<<dim3(36), dim3(256), 0, stream>>>(P[0], P[6], B1p, 9, 280);
    pack_w_kernel<<<dim3(16), dim3(256), 0, stream>>>(P[4], P[10], B2p, 4, 128);
    pack_w128_kernel<<<dim3(8),  dim3(256), 0, stream>>>(P[12], W1q, 4, 128);
    pack_w128_kernel<<<dim3(8),  dim3(256), 0, stream>>>(P[16], W2q, 4, 128);
    pack_w128_kernel<<<dim3(16), dim3(256), 0, stream>>>(P[18], W1o, 8, 256);
    pack_w128_kernel<<<dim3(8),  dim3(256), 0, stream>>>(P[22], W2o, 4, 128);

    // q = MLP_xq(h) -> bf16   (MFMA)
    node_mlp_mfma_kernel<128, unsigned short><<<dim3((N + 127) / 128), dim3(256), 0, stream>>>(
        h_bf, nullptr, nullptr, W1q, W2q, P[13], P[14], P[15], P[17], q_bf, N);

    // per-edge fused k/v MLPs (MFMA) + scores + exp + den + fused scatter
    kv_mfma_kernel<<<dim3((E + 63) / 64), dim3(256), 0, stream>>>(
        h_bf, q_bf, r_feat, edge_feat, e_w, src, dst, B1p, B2p,
        P[1], P[7], P[2], P[3], P[8], P[9], P[5], P[11],
        attn, den, E);

    // final = MLP_out([attn/den | h])   (MFMA, normalization in staging)
    node_mlp_mfma_kernel<256, float><<<dim3((N + 127) / 128), dim3(256), 0, stream>>>(
        h_bf, attn, den, W1o, W2o, P[19], P[20], P[21], P[23], (float*)d_out, N);
}

// Round 7
// 656.509 us; speedup vs baseline: 2.0954x; 2.0954x over previous
//
#include <hip/hip_runtime.h>
#include <hip/hip_bf16.h>

#define LN_EPS 1e-5f

typedef __attribute__((ext_vector_type(8))) short bf16x8;
typedef __attribute__((ext_vector_type(4))) float f32x4;

static __device__ __forceinline__ unsigned short f2bf(float x) {
    unsigned int u = __float_as_uint(x);
    return (unsigned short)((u + 0x7FFFu + ((u >> 16) & 1u)) >> 16);
}
static __device__ __forceinline__ float bf2f(unsigned short u) {
    return __uint_as_float(((unsigned int)u) << 16);
}
static __device__ __forceinline__ uint2 pack4bf(float a, float b, float c, float d) {
    uint2 r;
    r.x = (unsigned int)f2bf(a) | ((unsigned int)f2bf(b) << 16);
    r.y = (unsigned int)f2bf(c) | ((unsigned int)f2bf(d) << 16);
    return r;
}

// ---------------------------------------------------------------------------
// Weight packers: fragment-ready layout for mfma_f32_16x16x32_bf16 A-operand.
// Tile (kb, nt), lane l: m = nt*16 + (l&15), k = kb*32 + (l>>4)*8 + i (16B run).
// ---------------------------------------------------------------------------
__global__ void pack_w_kernel(const float* __restrict__ Wk, const float* __restrict__ Wv,
                              unsigned short* __restrict__ Bp, int KB, int Kreal)
{
    int idx = blockIdx.x * 256 + threadIdx.x;
    if (idx >= KB * 1024) return;
    int kb = idx >> 10, rem = idx & 1023, nt = rem >> 6, l = rem & 63;
    int n_g = nt * 16 + (l & 15);
    int kbase = kb * 32 + ((l >> 4) * 8);
    const float* W = (n_g < 128) ? Wk : Wv;
    int n = (n_g < 128) ? n_g : n_g - 128;
    unsigned short o[8];
    #pragma unroll
    for (int i = 0; i < 8; ++i) {
        int k = kbase + i;
        o[i] = (k < Kreal) ? f2bf(W[(size_t)k * 128 + n]) : (unsigned short)0;
    }
    *(int4*)(Bp + (size_t)idx * 8) = *(const int4*)o;
}

__global__ void pack_w128_kernel(const float* __restrict__ W,
                                 unsigned short* __restrict__ Bp, int KB, int Kreal)
{
    int idx = blockIdx.x * 256 + threadIdx.x;
    if (idx >= KB * 512) return;
    int kb = idx >> 9, rem = idx & 511, nt = rem >> 6, l = rem & 63;
    int n = nt * 16 + (l & 15);
    int kbase = kb * 32 + ((l >> 4) * 8);
    unsigned short o[8];
    #pragma unroll
    for (int i = 0; i < 8; ++i) {
        int k = kbase + i;
        o[i] = (k < Kreal) ? f2bf(W[(size_t)k * 128 + n]) : (unsigned short)0;
    }
    *(int4*)(Bp + (size_t)idx * 8) = *(const int4*)o;
}

__global__ void f32_to_bf16_kernel(const float* __restrict__ in,
                                   unsigned short* __restrict__ out, long n8)
{
    long i = (long)blockIdx.x * 256 + threadIdx.x;
    if (i >= n8) return;
    const float4* p = (const float4*)(in + i * 8);
    float4 a = p[0], b = p[1];
    unsigned short o[8] = { f2bf(a.x), f2bf(a.y), f2bf(a.z), f2bf(a.w),
                            f2bf(b.x), f2bf(b.y), f2bf(b.z), f2bf(b.w) };
    *(int4*)(out + i * 8) = *(const int4*)o;
}

// ---------------------------------------------------------------------------
// Node-side MFMA MLP: out = ReLU(LN(x @ W1 + b1)) @ W2 + b2, 128 rows/block.
// DIN=128: x = in_bf (bf16). DIN=256: x = [in_f (fp32) | in_bf], two K-passes
// through one a1[128][136] buffer (LDS < 64 KB limit). If den != null, the
// fp32 half is normalized per-head: x[col] *= (den[row][col>>3] > 0 ?
// 1/den[...] : 0)  — deferred softmax normalization of the attn accumulator.
// ---------------------------------------------------------------------------
template<int DIN, typename OUT>
__global__ __launch_bounds__(256, 2) void node_mlp_mfma_kernel(
    const unsigned short* __restrict__ in_bf, const float* __restrict__ in_f,
    const float* __restrict__ den,
    const unsigned short* __restrict__ W1p, const unsigned short* __restrict__ W2p,
    const float* __restrict__ b1, const float* __restrict__ g,
    const float* __restrict__ be, const float* __restrict__ b2,
    OUT* __restrict__ out, int nrows)
{
    constexpr int NPASS = DIN / 128;
    struct Smem {
        union __align__(16) {
            unsigned short a1[128][136];
            unsigned short a2[128][136];
        } u;
        float2 gbuf[128];
        float  b1buf[128], b2buf[128];
        float2 lnred[4][64];
        float2 lnstat[128];
    };
    __shared__ Smem sm;

    const int tid = threadIdx.x;
    const int w = tid >> 6, l = tid & 63, lg = l >> 4, li = l & 15;
    const int rt = w >> 1, ct = w & 1;
    const long r0 = (long)blockIdx.x * 128;

    if (tid < 128) {
        sm.gbuf[tid]  = make_float2(g[tid], be[tid]);
        sm.b1buf[tid] = b1[tid];
        sm.b2buf[tid] = b2[tid];
    }

    const int se = tid >> 1, sp = tid & 1;
    long srg = r0 + se; if (srg >= nrows) srg = nrows - 1;

    f32x4 acc[4][4];
    #pragma unroll
    for (int mt = 0; mt < 4; ++mt)
        #pragma unroll
        for (int et = 0; et < 4; ++et)
            acc[mt][et] = (f32x4){0.f, 0.f, 0.f, 0.f};

    // ---- layer 1: NPASS K-chunks of 128 through the shared a1 buffer
    #pragma unroll
    for (int pass = 0; pass < NPASS; ++pass) {
        if constexpr (NPASS == 2) {
            if (pass == 0) {
                // fp32 attn half, normalized by den (softmax denominator)
                float inv[8];
                const float4* dp = (const float4*)(den + (size_t)srg * 16 + sp * 8);
                float4 d0 = dp[0], d1 = dp[1];
                inv[0] = d0.x > 0.f ? 1.f / d0.x : 0.f;
                inv[1] = d0.y > 0.f ? 1.f / d0.y : 0.f;
                inv[2] = d0.z > 0.f ? 1.f / d0.z : 0.f;
                inv[3] = d0.w > 0.f ? 1.f / d0.w : 0.f;
                inv[4] = d1.x > 0.f ? 1.f / d1.x : 0.f;
                inv[5] = d1.y > 0.f ? 1.f / d1.y : 0.f;
                inv[6] = d1.z > 0.f ? 1.f / d1.z : 0.f;
                inv[7] = d1.w > 0.f ? 1.f / d1.w : 0.f;
                const float4* af = (const float4*)(in_f + (size_t)srg * 128 + sp * 64);
                #pragma unroll
                for (int i = 0; i < 16; ++i) {
                    float4 v = af[i];
                    float iv = inv[i >> 1];
                    *(uint2*)&sm.u.a1[se][sp * 64 + i * 4] =
                        pack4bf(v.x * iv, v.y * iv, v.z * iv, v.w * iv);
                }
            } else {
                const int4* s = (const int4*)(in_bf + (size_t)srg * 128 + sp * 64);
                int4* d = (int4*)&sm.u.a1[se][sp * 64];
                #pragma unroll
                for (int i = 0; i < 8; ++i) d[i] = s[i];   // 8 int4 = 64 bf16
            }
        } else {
            const int4* s = (const int4*)(in_bf + (size_t)srg * 128 + sp * 64);
            int4* d = (int4*)&sm.u.a1[se][sp * 64];
            #pragma unroll
            for (int i = 0; i < 8; ++i) d[i] = s[i];       // 8 int4 = 64 bf16
        }
        __syncthreads();

        #pragma unroll
        for (int kb = 0; kb < 4; ++kb) {
            bf16x8 wf[4], bfr[4];
            #pragma unroll
            for (int mt = 0; mt < 4; ++mt)
                wf[mt] = *(const bf16x8*)(W1p +
                    ((size_t)((pass * 4 + kb) * 8 + ct * 4 + mt) * 512 + l * 8));
            #pragma unroll
            for (int et = 0; et < 4; ++et)
                bfr[et] = *(const bf16x8*)(&sm.u.a1[rt * 64 + et * 16 + li][kb * 32 + lg * 8]);
            #pragma unroll
            for (int mt = 0; mt < 4; ++mt)
                #pragma unroll
                for (int et = 0; et < 4; ++et)
                    acc[mt][et] = __builtin_amdgcn_mfma_f32_16x16x32_bf16(
                        wf[mt], bfr[et], acc[mt][et], 0, 0, 0);
        }
        __syncthreads();   // a1 reads complete before restage / a2 overwrite
    }

    // ---- + b1, LN partials over this wave's 64 cols
    #pragma unroll
    for (int mt = 0; mt < 4; ++mt)
        #pragma unroll
        for (int r = 0; r < 4; ++r) {
            float b1v = sm.b1buf[ct * 64 + mt * 16 + lg * 4 + r];
            #pragma unroll
            for (int et = 0; et < 4; ++et) acc[mt][et][r] += b1v;
        }
    #pragma unroll
    for (int et = 0; et < 4; ++et) {
        float s = 0.f, sq = 0.f;
        #pragma unroll
        for (int mt = 0; mt < 4; ++mt)
            #pragma unroll
            for (int r = 0; r < 4; ++r) {
                float x = acc[mt][et][r];
                s += x; sq += x * x;
            }
        s  += __shfl_xor(s, 16, 64);  sq += __shfl_xor(sq, 16, 64);
        s  += __shfl_xor(s, 32, 64);  sq += __shfl_xor(sq, 32, 64);
        if (lg == 0) sm.lnred[w][et * 16 + li] = make_float2(s, sq);
    }
    __syncthreads();
    if (tid < 128) {
        int row = tid, rr = row >> 6;
        float2 p0 = sm.lnred[rr * 2][row & 63], p1 = sm.lnred[rr * 2 + 1][row & 63];
        float mu  = (p0.x + p1.x) * (1.f / 128.f);
        float var = (p0.y + p1.y) * (1.f / 128.f) - mu * mu;
        sm.lnstat[row] = make_float2(mu, rsqrtf(var + LN_EPS));
    }
    __syncthreads();

    // ---- normalize + ReLU -> a2 (bf16)
    {
        float2 stat[4];
        #pragma unroll
        for (int et = 0; et < 4; ++et) stat[et] = sm.lnstat[rt * 64 + et * 16 + li];
        #pragma unroll
        for (int mt = 0; mt < 4; ++mt) {
            float2 gb[4];
            #pragma unroll
            for (int r = 0; r < 4; ++r) gb[r] = sm.gbuf[ct * 64 + mt * 16 + lg * 4 + r];
            #pragma unroll
            for (int et = 0; et < 4; ++et) {
                float x0 = fmaxf(fmaf((acc[mt][et][0] - stat[et].x) * stat[et].y, gb[0].x, gb[0].y), 0.f);
                float x1 = fmaxf(fmaf((acc[mt][et][1] - stat[et].x) * stat[et].y, gb[1].x, gb[1].y), 0.f);
                float x2 = fmaxf(fmaf((acc[mt][et][2] - stat[et].x) * stat[et].y, gb[2].x, gb[2].y), 0.f);
                float x3 = fmaxf(fmaf((acc[mt][et][3] - stat[et].x) * stat[et].y, gb[3].x, gb[3].y), 0.f);
                *(uint2*)&sm.u.a2[rt * 64 + et * 16 + li][ct * 64 + mt * 16 + lg * 4] =
                    pack4bf(x0, x1, x2, x3);
            }
        }
    }
    __syncthreads();

    // ---- layer 2
    #pragma unroll
    for (int mt = 0; mt < 4; ++mt)
        #pragma unroll
        for (int et = 0; et < 4; ++et)
            acc[mt][et] = (f32x4){0.f, 0.f, 0.f, 0.f};

    for (int kb = 0; kb < 4; ++kb) {
        bf16x8 wf[4], bfr[4];
        #pragma unroll
        for (int mt = 0; mt < 4; ++mt)
            wf[mt] = *(const bf16x8*)(W2p + ((size_t)(kb * 8 + ct * 4 + mt) * 512 + l * 8));
        #pragma unroll
        for (int et = 0; et < 4; ++et)
            bfr[et] = *(const bf16x8*)(&sm.u.a2[rt * 64 + et * 16 + li][kb * 32 + lg * 8]);
        #pragma unroll
        for (int mt = 0; mt < 4; ++mt)
            #pragma unroll
            for (int et = 0; et < 4; ++et)
                acc[mt][et] = __builtin_amdgcn_mfma_f32_16x16x32_bf16(
                    wf[mt], bfr[et], acc[mt][et], 0, 0, 0);
    }

    // ---- epilogue: + b2, store
    float b2v[4][4];
    #pragma unroll
    for (int mt = 0; mt < 4; ++mt)
        #pragma unroll
        for (int r = 0; r < 4; ++r)
            b2v[mt][r] = sm.b2buf[ct * 64 + mt * 16 + lg * 4 + r];
    #pragma unroll
    for (int et = 0; et < 4; ++et) {
        long rg = r0 + rt * 64 + et * 16 + li;
        if (rg < nrows) {
            #pragma unroll
            for (int mt = 0; mt < 4; ++mt) {
                float y0 = acc[mt][et][0] + b2v[mt][0];
                float y1 = acc[mt][et][1] + b2v[mt][1];
                float y2 = acc[mt][et][2] + b2v[mt][2];
                float y3 = acc[mt][et][3] + b2v[mt][3];
                size_t o = (size_t)rg * 128 + ct * 64 + mt * 16 + lg * 4;
                if constexpr (sizeof(OUT) == 2) {
                    *(uint2*)(out + o) = pack4bf(y0, y1, y2, y3);
                } else {
                    float4 v = make_float4(y0, y1, y2, y3);
                    *(float4*)((float*)out + o) = v;
                }
            }
        }
    }
}

// ---------------------------------------------------------------------------
// MFMA edge kernel: 64 edges/block, fused xk|xv MLPs (256 output cols),
// LN+ReLU between layers. Epilogue: scores (k fp32 LDS · q from global) ->
// exp -> den atomics -> v scaled by ex*e_w staged to LDS (vbuf reuses the
// kbuf union space after scores consume it) -> COALESCED scatter: each wave
// handles (edge, 64-col half) pairs so one atomic instruction covers 64
// consecutive floats of one destination row (round-6 lesson: scattering
// straight from MFMA C-layout -> 64 cache lines/instr, 1.45 GB writes, 3x
// slowdown). Normalization deferred to the out-MLP staging.
// ---------------------------------------------------------------------------
__global__ __launch_bounds__(256, 3) void kv_mfma_kernel(
    const unsigned short* __restrict__ h_bf,   // [N][128] bf16
    const unsigned short* __restrict__ q_bf,   // [N][128] bf16
    const float* __restrict__ r_feat, const float* __restrict__ edge_feat,
    const float* __restrict__ e_w,
    const int* __restrict__ src_idx, const int* __restrict__ dst_idx,
    const unsigned short* __restrict__ B1p, const unsigned short* __restrict__ B2p,
    const float* __restrict__ kb1, const float* __restrict__ vb1,
    const float* __restrict__ kg,  const float* __restrict__ kbeta,
    const float* __restrict__ vg,  const float* __restrict__ vbeta,
    const float* __restrict__ kb2, const float* __restrict__ vb2,
    float* __restrict__ attn, float* __restrict__ den, int E)
{
    struct Smem {
        union __align__(16) {
            unsigned short a1[64][296];   // layer-1 input bf16 (280 + pad)
            unsigned short a2[64][264];   // layer-2 input bf16 (256 + pad)
            float          kbuf[64][132]; // k output fp32 (128 + pad)
            float          vbuf[64][132]; // scaled v fp32 (after scores)
        } u;                              // 37,888 B (~49 KB total -> 3 blk/CU)
        float  sex[64][17];               // exp(score) per edge x head (+pad)
        float2 gbuf[256];
        float  b1buf[256], b2buf[256];
        float2 lnred[4][64];
        float2 lnstat[2][64];
        int    sdst[64];
        float  sew[64];
    };
    __shared__ Smem sm;

    const int tid = threadIdx.x;
    const int w  = tid >> 6, l = tid & 63, lg = l >> 4, li = l & 15;
    const long e0 = (long)blockIdx.x * 64;

    {
        int c = tid;
        float g  = (c < 128) ? kg[c]    : vg[c - 128];
        float be = (c < 128) ? kbeta[c] : vbeta[c - 128];
        sm.gbuf[c]  = make_float2(g, be);
        sm.b1buf[c] = (c < 128) ? kb1[c] : vb1[c - 128];
        sm.b2buf[c] = (c < 128) ? kb2[c] : vb2[c - 128];
    }
    {
        int e = tid >> 2, qt = tid & 3;
        long eg = e0 + e; if (eg >= E) eg = E - 1;
        int d = dst_idx[eg], s = src_idx[eg];
        const int4* hd = (const int4*)(h_bf + (size_t)d * 128 + qt * 32);
        const int4* hs = (const int4*)(h_bf + (size_t)s * 128 + qt * 32);
        int4* a1d = (int4*)&sm.u.a1[e][24  + qt * 32];
        int4* a1s = (int4*)&sm.u.a1[e][152 + qt * 32];
        #pragma unroll
        for (int i = 0; i < 4; ++i) { a1d[i] = hd[i]; a1s[i] = hs[i]; }
        if (qt == 0) {
            float4 ef = *(const float4*)(edge_feat + (size_t)eg * 4);
            *(uint2*)&sm.u.a1[e][0] = pack4bf(ef.x, ef.y, ef.z, ef.w);
            const float4* rf = (const float4*)(r_feat + (size_t)eg * 20);
            #pragma unroll
            for (int i = 0; i < 5; ++i) {
                float4 v = rf[i];
                *(uint2*)&sm.u.a1[e][4 + i * 4] = pack4bf(v.x, v.y, v.z, v.w);
            }
            int4 z = {0,0,0,0};
            *(int4*)&sm.u.a1[e][280] = z;
            *(int4*)&sm.u.a1[e][288] = z;
        } else if (qt == 1) {
            sm.sdst[e] = d;
            sm.sew[e]  = e_w[eg];
        }
    }
    __syncthreads();

    f32x4 acc[4][4];
    #pragma unroll
    for (int mt = 0; mt < 4; ++mt)
        #pragma unroll
        for (int et = 0; et < 4; ++et)
            acc[mt][et] = (f32x4){0.f, 0.f, 0.f, 0.f};

    for (int kb = 0; kb < 9; ++kb) {
        bf16x8 wf[4], bfr[4];
        #pragma unroll
        for (int mt = 0; mt < 4; ++mt)
            wf[mt] = *(const bf16x8*)(B1p + ((size_t)(kb * 16 + w * 4 + mt) * 512 + l * 8));
        #pragma unroll
        for (int et = 0; et < 4; ++et)
            bfr[et] = *(const bf16x8*)(&sm.u.a1[et * 16 + li][kb * 32 + lg * 8]);
        #pragma unroll
        for (int mt = 0; mt < 4; ++mt)
            #pragma unroll
            for (int et = 0; et < 4; ++et)
                acc[mt][et] = __builtin_amdgcn_mfma_f32_16x16x32_bf16(
                    wf[mt], bfr[et], acc[mt][et], 0, 0, 0);
    }

    #pragma unroll
    for (int mt = 0; mt < 4; ++mt)
        #pragma unroll
        for (int r = 0; r < 4; ++r) {
            float b1v = sm.b1buf[w * 64 + mt * 16 + lg * 4 + r];
            #pragma unroll
            for (int et = 0; et < 4; ++et) acc[mt][et][r] += b1v;
        }

    {
        #pragma unroll
        for (int et = 0; et < 4; ++et) {
            float s = 0.f, sq = 0.f;
            #pragma unroll
            for (int mt = 0; mt < 4; ++mt)
                #pragma unroll
                for (int r = 0; r < 4; ++r) {
                    float x = acc[mt][et][r];
                    s += x; sq += x * x;
                }
            s  += __shfl_xor(s, 16, 64);  sq += __shfl_xor(sq, 16, 64);
            s  += __shfl_xor(s, 32, 64);  sq += __shfl_xor(sq, 32, 64);
            if (lg == 0) sm.lnred[w][et * 16 + li] = make_float2(s, sq);
        }
    }
    __syncthreads();
    if (tid < 128) {
        int half = tid >> 6, e = tid & 63;
        float2 p0 = sm.lnred[half * 2][e], p1 = sm.lnred[half * 2 + 1][e];
        float mu  = (p0.x + p1.x) * (1.f / 128.f);
        float var = (p0.y + p1.y) * (1.f / 128.f) - mu * mu;
        sm.lnstat[half][e] = make_float2(mu, rsqrtf(var + LN_EPS));
    }
    __syncthreads();

    {
        float2 stat[4];
        #pragma unroll
        for (int et = 0; et < 4; ++et) stat[et] = sm.lnstat[w >> 1][et * 16 + li];
        #pragma unroll
        for (int mt = 0; mt < 4; ++mt) {
            float2 gb[4];
            #pragma unroll
            for (int r = 0; r < 4; ++r) gb[r] = sm.gbuf[w * 64 + mt * 16 + lg * 4 + r];
            #pragma unroll
            for (int et = 0; et < 4; ++et) {
                float x0 = fmaxf(fmaf((acc[mt][et][0] - stat[et].x) * stat[et].y, gb[0].x, gb[0].y), 0.f);
                float x1 = fmaxf(fmaf((acc[mt][et][1] - stat[et].x) * stat[et].y, gb[1].x, gb[1].y), 0.f);
                float x2 = fmaxf(fmaf((acc[mt][et][2] - stat[et].x) * stat[et].y, gb[2].x, gb[2].y), 0.f);
                float x3 = fmaxf(fmaf((acc[mt][et][3] - stat[et].x) * stat[et].y, gb[3].x, gb[3].y), 0.f);
                *(uint2*)&sm.u.a2[et * 16 + li][w * 64 + mt * 16 + lg * 4] = pack4bf(x0, x1, x2, x3);
            }
        }
    }
    __syncthreads();

    #pragma unroll
    for (int mt = 0; mt < 4; ++mt)
        #pragma unroll
        for (int et = 0; et < 4; ++et)
            acc[mt][et] = (f32x4){0.f, 0.f, 0.f, 0.f};

    const int koff = (w < 2) ? 0 : 128;
    for (int kb = 0; kb < 4; ++kb) {
        bf16x8 wf[4], bfr[4];
        #pragma unroll
        for (int mt = 0; mt < 4; ++mt)
            wf[mt] = *(const bf16x8*)(B2p + ((size_t)(kb * 16 + w * 4 + mt) * 512 + l * 8));
        #pragma unroll
        for (int et = 0; et < 4; ++et)
            bfr[et] = *(const bf16x8*)(&sm.u.a2[et * 16 + li][koff + kb * 32 + lg * 8]);
        #pragma unroll
        for (int mt = 0; mt < 4; ++mt)
            #pragma unroll
            for (int et = 0; et < 4; ++et)
                acc[mt][et] = __builtin_amdgcn_mfma_f32_16x16x32_bf16(
                    wf[mt], bfr[et], acc[mt][et], 0, 0, 0);
    }
    #pragma unroll
    for (int mt = 0; mt < 4; ++mt)
        #pragma unroll
        for (int r = 0; r < 4; ++r) {
            float b2v = sm.b2buf[w * 64 + mt * 16 + lg * 4 + r];
            #pragma unroll
            for (int et = 0; et < 4; ++et) acc[mt][et][r] += b2v;
        }
    __syncthreads();   // all a2 reads done before kbuf overwrites the union

    // ---- waves 0,1 stash k (fp32) to LDS; waves 2,3 keep v in registers
    if (w < 2) {
        #pragma unroll
        for (int mt = 0; mt < 4; ++mt)
            #pragma unroll
            for (int et = 0; et < 4; ++et)
                *(f32x4*)&sm.u.kbuf[et * 16 + li][w * 64 + mt * 16 + lg * 4] = acc[mt][et];
    }
    __syncthreads();

    // ---- scores: 64 edges x 16 heads; q gathered from global (L2-resident)
    {
        int e = tid >> 2, hb = (tid & 3) * 4;
        long eg = e0 + e;
        int d = sm.sdst[e];
        const int4* qp = (const int4*)(q_bf + (size_t)d * 128 + hb * 8);
        int4 q4[4];
        #pragma unroll
        for (int i = 0; i < 4; ++i) q4[i] = qp[i];
        if (eg < E) {
            #pragma unroll
            for (int hh = 0; hh < 4; ++hh) {
                const float* kr = &sm.u.kbuf[e][(hb + hh) * 8];
                const unsigned short* qq = (const unsigned short*)&q4[hh];
                float sc = 0.f;
                #pragma unroll
                for (int t = 0; t < 8; ++t) sc = fmaf(kr[t], bf2f(qq[t]), sc);
                sc *= 0.35355339059327373f;   // 1/sqrt(8)
                float exv = __expf(sc);
                sm.sex[e][hb + hh] = exv;
                unsafeAtomicAdd(&den[(size_t)d * 16 + hb + hh], exv);
            }
        }
    }
    __syncthreads();   // sex ready; kbuf fully consumed

    // ---- waves 2,3: scale v by ex*e_w, stage to vbuf (kbuf's space)
    if (w >= 2) {
        #pragma unroll
        for (int et = 0; et < 4; ++et) {
            int e = et * 16 + li;
            long eg = e0 + e;
            float ew = (eg < E) ? sm.sew[e] : 0.f;
            #pragma unroll
            for (int mt = 0; mt < 4; ++mt) {
                int cbase = (w - 2) * 64 + mt * 16 + lg * 4;
                float scale = ew * sm.sex[e][cbase >> 3];
                f32x4 v = acc[mt][et];
                v[0] *= scale; v[1] *= scale; v[2] *= scale; v[3] *= scale;
                *(f32x4*)&sm.u.vbuf[e][cbase] = v;
            }
        }
    }
    __syncthreads();

    // ---- coalesced scatter: wave w handles (edge,half) pairs w*32..w*32+31;
    //      lane l covers 64 consecutive cols of one destination row.
    {
        #pragma unroll
        for (int j = 0; j < 32; ++j) {
            int idx = w * 32 + j;
            int e = idx >> 1, half = idx & 1;
            long eg = e0 + e;
            if (eg < E) {
                int d = sm.sdst[e];
                unsafeAtomicAdd(&attn[(size_t)d * 128 + half * 64 + l],
                                sm.u.vbuf[e][half * 64 + l]);
            }
        }
    }
}

// ---------------------------------------------------------------------------
extern "C" void kernel_launch(void* const* d_in, const int* in_sizes, int n_in,
                              void* d_out, int out_size, void* d_ws, size_t ws_size,
                              hipStream_t stream)
{
    const float* h         = (const float*)d_in[0];
    const float* r_feat    = (const float*)d_in[1];
    const float* edge_feat = (const float*)d_in[2];
    const int*   edge_idx  = (const int*)d_in[3];
    const float* e_w       = (const float*)d_in[4];
    const float* P[24];
    for (int i = 0; i < 24; ++i) P[i] = (const float*)d_in[5 + i];
    // P[0..5]=xk{W1,b1,g,beta,W2,b2}  P[6..11]=xv  P[12..17]=xq  P[18..23]=out

    const int N = in_sizes[0] / 128;
    const int E = in_sizes[4];
    const int* src = edge_idx;
    const int* dst = edge_idx + E;

    // workspace carve: h_bf | q_bf | B1p | B2p | W1q | W2q | W1o | W2o | attn | den
    char* p = (char*)d_ws;
    unsigned short* h_bf = (unsigned short*)p; p += (size_t)N * 128 * 2;
    unsigned short* q_bf = (unsigned short*)p; p += (size_t)N * 128 * 2;
    unsigned short* B1p  = (unsigned short*)p; p += (size_t)9 * 16 * 512 * 2;
    unsigned short* B2p  = (unsigned short*)p; p += (size_t)4 * 16 * 512 * 2;
    unsigned short* W1q  = (unsigned short*)p; p += (size_t)4 * 8 * 512 * 2;
    unsigned short* W2q  = (unsigned short*)p; p += (size_t)4 * 8 * 512 * 2;
    unsigned short* W1o  = (unsigned short*)p; p += (size_t)8 * 8 * 512 * 2;
    unsigned short* W2o  = (unsigned short*)p; p += (size_t)4 * 8 * 512 * 2;
    float* attn          = (float*)p;          p += (size_t)N * 128 * 4;
    float* den           = (float*)p;          p += (size_t)N * 16 * 4;

    // zero attn + den (adjacent)
    hipMemsetAsync(attn, 0, (size_t)N * 144 * sizeof(float), stream);

    // prep: h -> bf16; pack all weights
    f32_to_bf16_kernel<<<dim3((N * 128 / 8 + 255) / 256), dim3(256), 0, stream>>>(
        h, h_bf, (long)N * 128 / 8);
    pack_w_kernel<<<dim3(36), dim3(256), 0, stream>>>(P[0], P[6], B1p, 9, 280);
    pack_w_kernel<<<dim3(16), dim3(256), 0, stream>>>(P[4], P[10], B2p, 4, 128);
    pack_w128_kernel<<<dim3(8),  dim3(256), 0, stream>>>(P[12], W1q, 4, 128);
    pack_w128_kernel<<<dim3(8),  dim3(256), 0, stream>>>(P[16], W2q, 4, 128);
    pack_w128_kernel<<<dim3(16), dim3(256), 0, stream>>>(P[18], W1o, 8, 256);
    pack_w128_kernel<<<dim3(8),  dim3(256), 0, stream>>>(P[22], W2o, 4, 128);

    // q = MLP_xq(h) -> bf16   (MFMA)
    node_mlp_mfma_kernel<128, unsigned short><<<dim3((N + 127) / 128), dim3(256), 0, stream>>>(
        h_bf, nullptr, nullptr, W1q, W2q, P[13], P[14], P[15], P[17], q_bf, N);

    // per-edge fused k/v MLPs (MFMA) + scores + exp + den + coalesced scatter
    kv_mfma_kernel<<<dim3((E + 63) / 64), dim3(256), 0, stream>>>(
        h_bf, q_bf, r_feat, edge_feat, e_w, src, dst, B1p, B2p,
        P[1], P[7], P[2], P[3], P[8], P[9], P[5], P[11],
        attn, den, E);

    // final = MLP_out([attn/den | h])   (MFMA, normalization in staging)
    node_mlp_mfma_kernel<256, float><<<dim3((N + 127) / 128), dim3(256), 0, stream>>>(
        h_bf, attn, den, W1o, W2o, P[19], P[20], P[21], P[23], (float*)d_out, N);
}

// Round 8
// 542.657 us; speedup vs baseline: 2.5351x; 1.2098x over previous
//
#include <hip/hip_runtime.h>
#include <hip/hip_bf16.h>

#define LN_EPS 1e-5f

typedef __attribute__((ext_vector_type(8))) short bf16x8;
typedef __attribute__((ext_vector_type(4))) float f32x4;

static __device__ __forceinline__ unsigned short f2bf(float x) {
    unsigned int u = __float_as_uint(x);
    return (unsigned short)((u + 0x7FFFu + ((u >> 16) & 1u)) >> 16);
}
static __device__ __forceinline__ float bf2f(unsigned short u) {
    return __uint_as_float(((unsigned int)u) << 16);
}
static __device__ __forceinline__ uint2 pack4bf(float a, float b, float c, float d) {
    uint2 r;
    r.x = (unsigned int)f2bf(a) | ((unsigned int)f2bf(b) << 16);
    r.y = (unsigned int)f2bf(c) | ((unsigned int)f2bf(d) << 16);
    return r;
}

// ---------------------------------------------------------------------------
// Merged weight packer: fragment-ready layout for mfma A-operand.
// Tile (kb, nt), lane l: m = nt*16 + (l&15), k = kb*32 + (l>>4)*8 + i.
// Block ranges: [0,36) B1p fused(280K) | [36,52) B2p fused(128K) |
// [52,60) W1q | [60,68) W2q | [68,84) W1o(256K) | [84,92) W2o.
// ---------------------------------------------------------------------------
static __device__ __forceinline__ void pack_w_body(
    const float* Wk, const float* Wv, unsigned short* Bp, int Kreal, int idx)
{
    int kb = idx >> 10, rem = idx & 1023, nt = rem >> 6, l = rem & 63;
    int n_g = nt * 16 + (l & 15);
    int kbase = kb * 32 + ((l >> 4) * 8);
    const float* W = (n_g < 128) ? Wk : Wv;
    int n = (n_g < 128) ? n_g : n_g - 128;
    unsigned short o[8];
    #pragma unroll
    for (int i = 0; i < 8; ++i) {
        int k = kbase + i;
        o[i] = (k < Kreal) ? f2bf(W[(size_t)k * 128 + n]) : (unsigned short)0;
    }
    *(int4*)(Bp + (size_t)idx * 8) = *(const int4*)o;
}
static __device__ __forceinline__ void pack_w128_body(
    const float* W, unsigned short* Bp, int Kreal, int idx)
{
    int kb = idx >> 9, rem = idx & 511, nt = rem >> 6, l = rem & 63;
    int n = nt * 16 + (l & 15);
    int kbase = kb * 32 + ((l >> 4) * 8);
    unsigned short o[8];
    #pragma unroll
    for (int i = 0; i < 8; ++i) {
        int k = kbase + i;
        o[i] = (k < Kreal) ? f2bf(W[(size_t)k * 128 + n]) : (unsigned short)0;
    }
    *(int4*)(Bp + (size_t)idx * 8) = *(const int4*)o;
}

__global__ void pack_all_kernel(
    const float* kW1, const float* vW1, const float* kW2, const float* vW2,
    const float* qW1, const float* qW2, const float* oW1, const float* oW2,
    unsigned short* B1p, unsigned short* B2p,
    unsigned short* W1q, unsigned short* W2q,
    unsigned short* W1o, unsigned short* W2o)
{
    int b = blockIdx.x, tid = threadIdx.x;
    if      (b < 36) pack_w_body(kW1, vW1, B1p, 280, b * 256 + tid);
    else if (b < 52) pack_w_body(kW2, vW2, B2p, 128, (b - 36) * 256 + tid);
    else if (b < 60) pack_w128_body(qW1, W1q, 128, (b - 52) * 256 + tid);
    else if (b < 68) pack_w128_body(qW2, W2q, 128, (b - 60) * 256 + tid);
    else if (b < 84) pack_w128_body(oW1, W1o, 256, (b - 68) * 256 + tid);
    else             pack_w128_body(oW2, W2o, 128, (b - 84) * 256 + tid);
}

// ---------------------------------------------------------------------------
// Node-side MFMA MLP: out = ReLU(LN(x @ W1 + b1)) @ W2 + b2, 128 rows/block.
// DIN=128 (q-MLP): stages from in_f32 (h fp32), converts to bf16 in-flight,
//   and writes the bf16 copy to hbf_out (fuses the old f32->bf16 pass).
// DIN=256 (out-MLP): pass0 = attn_bf (bf16, unnormalized) scaled per-head by
//   1/den (deferred softmax normalization); pass1 = in_bf (h_bf).
// ---------------------------------------------------------------------------
template<int DIN, typename OUT>
__global__ __launch_bounds__(256, 2) void node_mlp_mfma_kernel(
    const unsigned short* __restrict__ in_bf,   // DIN=256 pass-1 source (h_bf)
    const float* __restrict__ in_f32,           // DIN=128 fp32 source (h)
    const unsigned short* __restrict__ attn_bf, // DIN=256 pass-0 source
    const float* __restrict__ den,              // DIN=256 denominators
    unsigned short* __restrict__ hbf_out,       // DIN=128 bf16 side output
    const unsigned short* __restrict__ W1p, const unsigned short* __restrict__ W2p,
    const float* __restrict__ b1, const float* __restrict__ g,
    const float* __restrict__ be, const float* __restrict__ b2,
    OUT* __restrict__ out, int nrows)
{
    constexpr int NPASS = DIN / 128;
    struct Smem {
        union __align__(16) {
            unsigned short a1[128][136];
            unsigned short a2[128][136];
        } u;
        float2 gbuf[128];
        float  b1buf[128], b2buf[128];
        float2 lnred[4][64];
        float2 lnstat[128];
    };
    __shared__ Smem sm;

    const int tid = threadIdx.x;
    const int w = tid >> 6, l = tid & 63, lg = l >> 4, li = l & 15;
    const int rt = w >> 1, ct = w & 1;
    const long r0 = (long)blockIdx.x * 128;

    if (tid < 128) {
        sm.gbuf[tid]  = make_float2(g[tid], be[tid]);
        sm.b1buf[tid] = b1[tid];
        sm.b2buf[tid] = b2[tid];
    }

    const int se = tid >> 1, sp = tid & 1;
    long srg = r0 + se; if (srg >= nrows) srg = nrows - 1;

    f32x4 acc[4][4];
    #pragma unroll
    for (int mt = 0; mt < 4; ++mt)
        #pragma unroll
        for (int et = 0; et < 4; ++et)
            acc[mt][et] = (f32x4){0.f, 0.f, 0.f, 0.f};

    // ---- layer 1: NPASS K-chunks of 128 through the shared a1 buffer
    #pragma unroll
    for (int pass = 0; pass < NPASS; ++pass) {
        if constexpr (NPASS == 2) {
            if (pass == 0) {
                // bf16 attn half, normalized per-head by den
                float inv[8];
                const float4* dp = (const float4*)(den + (size_t)srg * 16 + sp * 8);
                float4 d0 = dp[0], d1 = dp[1];
                inv[0] = d0.x > 0.f ? 1.f / d0.x : 0.f;
                inv[1] = d0.y > 0.f ? 1.f / d0.y : 0.f;
                inv[2] = d0.z > 0.f ? 1.f / d0.z : 0.f;
                inv[3] = d0.w > 0.f ? 1.f / d0.w : 0.f;
                inv[4] = d1.x > 0.f ? 1.f / d1.x : 0.f;
                inv[5] = d1.y > 0.f ? 1.f / d1.y : 0.f;
                inv[6] = d1.z > 0.f ? 1.f / d1.z : 0.f;
                inv[7] = d1.w > 0.f ? 1.f / d1.w : 0.f;
                const int4* ap = (const int4*)(attn_bf + (size_t)srg * 128 + sp * 64);
                #pragma unroll
                for (int i = 0; i < 8; ++i) {   // 8 bf16 per iter = one head
                    int4 raw = ap[i];
                    const unsigned short* u = (const unsigned short*)&raw;
                    float iv = inv[i];
                    *(uint2*)&sm.u.a1[se][sp * 64 + i * 8] =
                        pack4bf(bf2f(u[0])*iv, bf2f(u[1])*iv, bf2f(u[2])*iv, bf2f(u[3])*iv);
                    *(uint2*)&sm.u.a1[se][sp * 64 + i * 8 + 4] =
                        pack4bf(bf2f(u[4])*iv, bf2f(u[5])*iv, bf2f(u[6])*iv, bf2f(u[7])*iv);
                }
            } else {
                const int4* s = (const int4*)(in_bf + (size_t)srg * 128 + sp * 64);
                int4* d = (int4*)&sm.u.a1[se][sp * 64];
                #pragma unroll
                for (int i = 0; i < 8; ++i) d[i] = s[i];   // 8 int4 = 64 bf16
            }
        } else {
            // DIN=128: convert fp32 h -> bf16, stage + write out
            const float4* af = (const float4*)(in_f32 + (size_t)srg * 128 + sp * 64);
            int4 tmp4[8];
            uint2* tp = (uint2*)tmp4;
            #pragma unroll
            for (int i = 0; i < 16; ++i) {
                float4 v = af[i];
                tp[i] = pack4bf(v.x, v.y, v.z, v.w);
            }
            int4* ldst = (int4*)&sm.u.a1[se][sp * 64];
            int4* gdst = (int4*)(hbf_out + (size_t)srg * 128 + sp * 64);
            #pragma unroll
            for (int k = 0; k < 8; ++k) { ldst[k] = tmp4[k]; gdst[k] = tmp4[k]; }
        }
        __syncthreads();

        #pragma unroll
        for (int kb = 0; kb < 4; ++kb) {
            bf16x8 wf[4], bfr[4];
            #pragma unroll
            for (int mt = 0; mt < 4; ++mt)
                wf[mt] = *(const bf16x8*)(W1p +
                    ((size_t)((pass * 4 + kb) * 8 + ct * 4 + mt) * 512 + l * 8));
            #pragma unroll
            for (int et = 0; et < 4; ++et)
                bfr[et] = *(const bf16x8*)(&sm.u.a1[rt * 64 + et * 16 + li][kb * 32 + lg * 8]);
            #pragma unroll
            for (int mt = 0; mt < 4; ++mt)
                #pragma unroll
                for (int et = 0; et < 4; ++et)
                    acc[mt][et] = __builtin_amdgcn_mfma_f32_16x16x32_bf16(
                        wf[mt], bfr[et], acc[mt][et], 0, 0, 0);
        }
        __syncthreads();   // a1 reads complete before restage / a2 overwrite
    }

    // ---- + b1, LN partials over this wave's 64 cols
    #pragma unroll
    for (int mt = 0; mt < 4; ++mt)
        #pragma unroll
        for (int r = 0; r < 4; ++r) {
            float b1v = sm.b1buf[ct * 64 + mt * 16 + lg * 4 + r];
            #pragma unroll
            for (int et = 0; et < 4; ++et) acc[mt][et][r] += b1v;
        }
    #pragma unroll
    for (int et = 0; et < 4; ++et) {
        float s = 0.f, sq = 0.f;
        #pragma unroll
        for (int mt = 0; mt < 4; ++mt)
            #pragma unroll
            for (int r = 0; r < 4; ++r) {
                float x = acc[mt][et][r];
                s += x; sq += x * x;
            }
        s  += __shfl_xor(s, 16, 64);  sq += __shfl_xor(sq, 16, 64);
        s  += __shfl_xor(s, 32, 64);  sq += __shfl_xor(sq, 32, 64);
        if (lg == 0) sm.lnred[w][et * 16 + li] = make_float2(s, sq);
    }
    __syncthreads();
    if (tid < 128) {
        int row = tid, rr = row >> 6;
        float2 p0 = sm.lnred[rr * 2][row & 63], p1 = sm.lnred[rr * 2 + 1][row & 63];
        float mu  = (p0.x + p1.x) * (1.f / 128.f);
        float var = (p0.y + p1.y) * (1.f / 128.f) - mu * mu;
        sm.lnstat[row] = make_float2(mu, rsqrtf(var + LN_EPS));
    }
    __syncthreads();

    // ---- normalize + ReLU -> a2 (bf16)
    {
        float2 stat[4];
        #pragma unroll
        for (int et = 0; et < 4; ++et) stat[et] = sm.lnstat[rt * 64 + et * 16 + li];
        #pragma unroll
        for (int mt = 0; mt < 4; ++mt) {
            float2 gb[4];
            #pragma unroll
            for (int r = 0; r < 4; ++r) gb[r] = sm.gbuf[ct * 64 + mt * 16 + lg * 4 + r];
            #pragma unroll
            for (int et = 0; et < 4; ++et) {
                float x0 = fmaxf(fmaf((acc[mt][et][0] - stat[et].x) * stat[et].y, gb[0].x, gb[0].y), 0.f);
                float x1 = fmaxf(fmaf((acc[mt][et][1] - stat[et].x) * stat[et].y, gb[1].x, gb[1].y), 0.f);
                float x2 = fmaxf(fmaf((acc[mt][et][2] - stat[et].x) * stat[et].y, gb[2].x, gb[2].y), 0.f);
                float x3 = fmaxf(fmaf((acc[mt][et][3] - stat[et].x) * stat[et].y, gb[3].x, gb[3].y), 0.f);
                *(uint2*)&sm.u.a2[rt * 64 + et * 16 + li][ct * 64 + mt * 16 + lg * 4] =
                    pack4bf(x0, x1, x2, x3);
            }
        }
    }
    __syncthreads();

    // ---- layer 2
    #pragma unroll
    for (int mt = 0; mt < 4; ++mt)
        #pragma unroll
        for (int et = 0; et < 4; ++et)
            acc[mt][et] = (f32x4){0.f, 0.f, 0.f, 0.f};

    for (int kb = 0; kb < 4; ++kb) {
        bf16x8 wf[4], bfr[4];
        #pragma unroll
        for (int mt = 0; mt < 4; ++mt)
            wf[mt] = *(const bf16x8*)(W2p + ((size_t)(kb * 8 + ct * 4 + mt) * 512 + l * 8));
        #pragma unroll
        for (int et = 0; et < 4; ++et)
            bfr[et] = *(const bf16x8*)(&sm.u.a2[rt * 64 + et * 16 + li][kb * 32 + lg * 8]);
        #pragma unroll
        for (int mt = 0; mt < 4; ++mt)
            #pragma unroll
            for (int et = 0; et < 4; ++et)
                acc[mt][et] = __builtin_amdgcn_mfma_f32_16x16x32_bf16(
                    wf[mt], bfr[et], acc[mt][et], 0, 0, 0);
    }

    // ---- epilogue: + b2, store
    float b2v[4][4];
    #pragma unroll
    for (int mt = 0; mt < 4; ++mt)
        #pragma unroll
        for (int r = 0; r < 4; ++r)
            b2v[mt][r] = sm.b2buf[ct * 64 + mt * 16 + lg * 4 + r];
    #pragma unroll
    for (int et = 0; et < 4; ++et) {
        long rg = r0 + rt * 64 + et * 16 + li;
        if (rg < nrows) {
            #pragma unroll
            for (int mt = 0; mt < 4; ++mt) {
                float y0 = acc[mt][et][0] + b2v[mt][0];
                float y1 = acc[mt][et][1] + b2v[mt][1];
                float y2 = acc[mt][et][2] + b2v[mt][2];
                float y3 = acc[mt][et][3] + b2v[mt][3];
                size_t o = (size_t)rg * 128 + ct * 64 + mt * 16 + lg * 4;
                if constexpr (sizeof(OUT) == 2) {
                    *(uint2*)(out + o) = pack4bf(y0, y1, y2, y3);
                } else {
                    float4 v = make_float4(y0, y1, y2, y3);
                    *(float4*)((float*)out + o) = v;
                }
            }
        }
    }
}

// ---------------------------------------------------------------------------
// MFMA edge kernel: 64 edges/block, fused xk|xv MLPs (256 output cols),
// LN+ReLU between layers. Epilogue: scores -> exp -> den atomics -> v scaled
// by ex*e_w staged to LDS -> coalesced scatter into bf16 attn accumulator via
// global_atomic_pk_add_bf16 (one wave per edge: 64 lanes x 2 bf16 = the full
// 128-col row in ONE instruction, 4 cache lines — halves round-7's atomic
// line-RMW traffic). Normalization deferred to out-MLP staging; safe in bf16
// because the unnormalized accumulator is ~den (≈E/N=12)x the final value.
// ---------------------------------------------------------------------------
__global__ __launch_bounds__(256, 3) void kv_mfma_kernel(
    const unsigned short* __restrict__ h_bf,   // [N][128] bf16
    const unsigned short* __restrict__ q_bf,   // [N][128] bf16
    const float* __restrict__ r_feat, const float* __restrict__ edge_feat,
    const float* __restrict__ e_w,
    const int* __restrict__ src_idx, const int* __restrict__ dst_idx,
    const unsigned short* __restrict__ B1p, const unsigned short* __restrict__ B2p,
    const float* __restrict__ kb1, const float* __restrict__ vb1,
    const float* __restrict__ kg,  const float* __restrict__ kbeta,
    const float* __restrict__ vg,  const float* __restrict__ vbeta,
    const float* __restrict__ kb2, const float* __restrict__ vb2,
    unsigned short* __restrict__ attn_bf, float* __restrict__ den, int E)
{
    struct Smem {
        union __align__(16) {
            unsigned short a1[64][296];   // layer-1 input bf16 (280 + pad)
            unsigned short a2[64][264];   // layer-2 input bf16 (256 + pad)
            float          kbuf[64][132]; // k output fp32 (128 + pad)
            float          vbuf[64][132]; // scaled v fp32 (after scores)
        } u;
        float  sex[64][17];               // exp(score) per edge x head (+pad)
        float2 gbuf[256];
        float  b1buf[256], b2buf[256];
        float2 lnred[4][64];
        float2 lnstat[2][64];
        int    sdst[64];
        float  sew[64];
    };
    __shared__ Smem sm;

    const int tid = threadIdx.x;
    const int w  = tid >> 6, l = tid & 63, lg = l >> 4, li = l & 15;
    const long e0 = (long)blockIdx.x * 64;

    {
        int c = tid;
        float g  = (c < 128) ? kg[c]    : vg[c - 128];
        float be = (c < 128) ? kbeta[c] : vbeta[c - 128];
        sm.gbuf[c]  = make_float2(g, be);
        sm.b1buf[c] = (c < 128) ? kb1[c] : vb1[c - 128];
        sm.b2buf[c] = (c < 128) ? kb2[c] : vb2[c - 128];
    }
    {
        int e = tid >> 2, qt = tid & 3;
        long eg = e0 + e; if (eg >= E) eg = E - 1;
        int d = dst_idx[eg], s = src_idx[eg];
        const int4* hd = (const int4*)(h_bf + (size_t)d * 128 + qt * 32);
        const int4* hs = (const int4*)(h_bf + (size_t)s * 128 + qt * 32);
        int4* a1d = (int4*)&sm.u.a1[e][24  + qt * 32];
        int4* a1s = (int4*)&sm.u.a1[e][152 + qt * 32];
        #pragma unroll
        for (int i = 0; i < 4; ++i) { a1d[i] = hd[i]; a1s[i] = hs[i]; }
        if (qt == 0) {
            float4 ef = *(const float4*)(edge_feat + (size_t)eg * 4);
            *(uint2*)&sm.u.a1[e][0] = pack4bf(ef.x, ef.y, ef.z, ef.w);
            const float4* rf = (const float4*)(r_feat + (size_t)eg * 20);
            #pragma unroll
            for (int i = 0; i < 5; ++i) {
                float4 v = rf[i];
                *(uint2*)&sm.u.a1[e][4 + i * 4] = pack4bf(v.x, v.y, v.z, v.w);
            }
            int4 z = {0,0,0,0};
            *(int4*)&sm.u.a1[e][280] = z;
            *(int4*)&sm.u.a1[e][288] = z;
        } else if (qt == 1) {
            sm.sdst[e] = d;
            sm.sew[e]  = e_w[eg];
        }
    }
    __syncthreads();

    f32x4 acc[4][4];
    #pragma unroll
    for (int mt = 0; mt < 4; ++mt)
        #pragma unroll
        for (int et = 0; et < 4; ++et)
            acc[mt][et] = (f32x4){0.f, 0.f, 0.f, 0.f};

    for (int kb = 0; kb < 9; ++kb) {
        bf16x8 wf[4], bfr[4];
        #pragma unroll
        for (int mt = 0; mt < 4; ++mt)
            wf[mt] = *(const bf16x8*)(B1p + ((size_t)(kb * 16 + w * 4 + mt) * 512 + l * 8));
        #pragma unroll
        for (int et = 0; et < 4; ++et)
            bfr[et] = *(const bf16x8*)(&sm.u.a1[et * 16 + li][kb * 32 + lg * 8]);
        #pragma unroll
        for (int mt = 0; mt < 4; ++mt)
            #pragma unroll
            for (int et = 0; et < 4; ++et)
                acc[mt][et] = __builtin_amdgcn_mfma_f32_16x16x32_bf16(
                    wf[mt], bfr[et], acc[mt][et], 0, 0, 0);
    }

    #pragma unroll
    for (int mt = 0; mt < 4; ++mt)
        #pragma unroll
        for (int r = 0; r < 4; ++r) {
            float b1v = sm.b1buf[w * 64 + mt * 16 + lg * 4 + r];
            #pragma unroll
            for (int et = 0; et < 4; ++et) acc[mt][et][r] += b1v;
        }

    {
        #pragma unroll
        for (int et = 0; et < 4; ++et) {
            float s = 0.f, sq = 0.f;
            #pragma unroll
            for (int mt = 0; mt < 4; ++mt)
                #pragma unroll
                for (int r = 0; r < 4; ++r) {
                    float x = acc[mt][et][r];
                    s += x; sq += x * x;
                }
            s  += __shfl_xor(s, 16, 64);  sq += __shfl_xor(sq, 16, 64);
            s  += __shfl_xor(s, 32, 64);  sq += __shfl_xor(sq, 32, 64);
            if (lg == 0) sm.lnred[w][et * 16 + li] = make_float2(s, sq);
        }
    }
    __syncthreads();
    if (tid < 128) {
        int half = tid >> 6, e = tid & 63;
        float2 p0 = sm.lnred[half * 2][e], p1 = sm.lnred[half * 2 + 1][e];
        float mu  = (p0.x + p1.x) * (1.f / 128.f);
        float var = (p0.y + p1.y) * (1.f / 128.f) - mu * mu;
        sm.lnstat[half][e] = make_float2(mu, rsqrtf(var + LN_EPS));
    }
    __syncthreads();

    {
        float2 stat[4];
        #pragma unroll
        for (int et = 0; et < 4; ++et) stat[et] = sm.lnstat[w >> 1][et * 16 + li];
        #pragma unroll
        for (int mt = 0; mt < 4; ++mt) {
            float2 gb[4];
            #pragma unroll
            for (int r = 0; r < 4; ++r) gb[r] = sm.gbuf[w * 64 + mt * 16 + lg * 4 + r];
            #pragma unroll
            for (int et = 0; et < 4; ++et) {
                float x0 = fmaxf(fmaf((acc[mt][et][0] - stat[et].x) * stat[et].y, gb[0].x, gb[0].y), 0.f);
                float x1 = fmaxf(fmaf((acc[mt][et][1] - stat[et].x) * stat[et].y, gb[1].x, gb[1].y), 0.f);
                float x2 = fmaxf(fmaf((acc[mt][et][2] - stat[et].x) * stat[et].y, gb[2].x, gb[2].y), 0.f);
                float x3 = fmaxf(fmaf((acc[mt][et][3] - stat[et].x) * stat[et].y, gb[3].x, gb[3].y), 0.f);
                *(uint2*)&sm.u.a2[et * 16 + li][w * 64 + mt * 16 + lg * 4] = pack4bf(x0, x1, x2, x3);
            }
        }
    }
    __syncthreads();

    #pragma unroll
    for (int mt = 0; mt < 4; ++mt)
        #pragma unroll
        for (int et = 0; et < 4; ++et)
            acc[mt][et] = (f32x4){0.f, 0.f, 0.f, 0.f};

    const int koff = (w < 2) ? 0 : 128;
    for (int kb = 0; kb < 4; ++kb) {
        bf16x8 wf[4], bfr[4];
        #pragma unroll
        for (int mt = 0; mt < 4; ++mt)
            wf[mt] = *(const bf16x8*)(B2p + ((size_t)(kb * 16 + w * 4 + mt) * 512 + l * 8));
        #pragma unroll
        for (int et = 0; et < 4; ++et)
            bfr[et] = *(const bf16x8*)(&sm.u.a2[et * 16 + li][koff + kb * 32 + lg * 8]);
        #pragma unroll
        for (int mt = 0; mt < 4; ++mt)
            #pragma unroll
            for (int et = 0; et < 4; ++et)
                acc[mt][et] = __builtin_amdgcn_mfma_f32_16x16x32_bf16(
                    wf[mt], bfr[et], acc[mt][et], 0, 0, 0);
    }
    #pragma unroll
    for (int mt = 0; mt < 4; ++mt)
        #pragma unroll
        for (int r = 0; r < 4; ++r) {
            float b2v = sm.b2buf[w * 64 + mt * 16 + lg * 4 + r];
            #pragma unroll
            for (int et = 0; et < 4; ++et) acc[mt][et][r] += b2v;
        }
    __syncthreads();   // all a2 reads done before kbuf overwrites the union

    // ---- waves 0,1 stash k (fp32) to LDS; waves 2,3 keep v in registers
    if (w < 2) {
        #pragma unroll
        for (int mt = 0; mt < 4; ++mt)
            #pragma unroll
            for (int et = 0; et < 4; ++et)
                *(f32x4*)&sm.u.kbuf[et * 16 + li][w * 64 + mt * 16 + lg * 4] = acc[mt][et];
    }
    __syncthreads();

    // ---- scores: 64 edges x 16 heads; q gathered from global (L2-resident)
    {
        int e = tid >> 2, hb = (tid & 3) * 4;
        long eg = e0 + e;
        int d = sm.sdst[e];
        const int4* qp = (const int4*)(q_bf + (size_t)d * 128 + hb * 8);
        int4 q4[4];
        #pragma unroll
        for (int i = 0; i < 4; ++i) q4[i] = qp[i];
        if (eg < E) {
            #pragma unroll
            for (int hh = 0; hh < 4; ++hh) {
                const float* kr = &sm.u.kbuf[e][(hb + hh) * 8];
                const unsigned short* qq = (const unsigned short*)&q4[hh];
                float sc = 0.f;
                #pragma unroll
                for (int t = 0; t < 8; ++t) sc = fmaf(kr[t], bf2f(qq[t]), sc);
                sc *= 0.35355339059327373f;   // 1/sqrt(8)
                float exv = __expf(sc);
                sm.sex[e][hb + hh] = exv;
                unsafeAtomicAdd(&den[(size_t)d * 16 + hb + hh], exv);
            }
        }
    }
    __syncthreads();   // sex ready; kbuf fully consumed

    // ---- waves 2,3: scale v by ex*e_w, stage to vbuf (kbuf's space)
    if (w >= 2) {
        #pragma unroll
        for (int et = 0; et < 4; ++et) {
            int e = et * 16 + li;
            long eg = e0 + e;
            float ew = (eg < E) ? sm.sew[e] : 0.f;
            #pragma unroll
            for (int mt = 0; mt < 4; ++mt) {
                int cbase = (w - 2) * 64 + mt * 16 + lg * 4;
                float scale = ew * sm.sex[e][cbase >> 3];
                f32x4 v = acc[mt][et];
                v[0] *= scale; v[1] *= scale; v[2] *= scale; v[3] *= scale;
                *(f32x4*)&sm.u.vbuf[e][cbase] = v;
            }
        }
    }
    __syncthreads();

    // ---- coalesced bf16 scatter: one wave per edge, lane l covers cols
    //      2l,2l+1 -> whole 128-col row in one packed-bf16 atomic (4 lines).
    {
        #pragma unroll
        for (int j = 0; j < 16; ++j) {
            int e = w * 16 + j;
            long eg = e0 + e;
            if (eg < E) {
                int d = sm.sdst[e];
                float2 vv = *(const float2*)&sm.u.vbuf[e][l * 2];
                unsigned int pk = (unsigned int)f2bf(vv.x) |
                                  ((unsigned int)f2bf(vv.y) << 16);
                unsigned short* addr = attn_bf + (size_t)d * 128 + l * 2;
                asm volatile("global_atomic_pk_add_bf16 %0, %1, off"
                             :: "v"(addr), "v"(pk) : "memory");
            }
        }
    }
}

// ---------------------------------------------------------------------------
extern "C" void kernel_launch(void* const* d_in, const int* in_sizes, int n_in,
                              void* d_out, int out_size, void* d_ws, size_t ws_size,
                              hipStream_t stream)
{
    const float* h         = (const float*)d_in[0];
    const float* r_feat    = (const float*)d_in[1];
    const float* edge_feat = (const float*)d_in[2];
    const int*   edge_idx  = (const int*)d_in[3];
    const float* e_w       = (const float*)d_in[4];
    const float* P[24];
    for (int i = 0; i < 24; ++i) P[i] = (const float*)d_in[5 + i];
    // P[0..5]=xk{W1,b1,g,beta,W2,b2}  P[6..11]=xv  P[12..17]=xq  P[18..23]=out

    const int N = in_sizes[0] / 128;
    const int E = in_sizes[4];
    const int* src = edge_idx;
    const int* dst = edge_idx + E;

    // workspace carve: h_bf | q_bf | B1p | B2p | W1q | W2q | W1o | W2o |
    //                  attn_bf (bf16) | den (fp32, adjacent for one memset)
    char* p = (char*)d_ws;
    unsigned short* h_bf = (unsigned short*)p; p += (size_t)N * 128 * 2;
    unsigned short* q_bf = (unsigned short*)p; p += (size_t)N * 128 * 2;
    unsigned short* B1p  = (unsigned short*)p; p += (size_t)9 * 16 * 512 * 2;
    unsigned short* B2p  = (unsigned short*)p; p += (size_t)4 * 16 * 512 * 2;
    unsigned short* W1q  = (unsigned short*)p; p += (size_t)4 * 8 * 512 * 2;
    unsigned short* W2q  = (unsigned short*)p; p += (size_t)4 * 8 * 512 * 2;
    unsigned short* W1o  = (unsigned short*)p; p += (size_t)8 * 8 * 512 * 2;
    unsigned short* W2o  = (unsigned short*)p; p += (size_t)4 * 8 * 512 * 2;
    unsigned short* attn_bf = (unsigned short*)p; p += (size_t)N * 128 * 2;
    float* den           = (float*)p;          p += (size_t)N * 16 * 4;

    // zero attn_bf + den (adjacent)
    hipMemsetAsync(attn_bf, 0, (size_t)N * (128 * 2 + 16 * 4), stream);

    // pack all weights in one dispatch
    pack_all_kernel<<<dim3(92), dim3(256), 0, stream>>>(
        P[0], P[6], P[4], P[10], P[12], P[16], P[18], P[22],
        B1p, B2p, W1q, W2q, W1o, W2o);

    // q = MLP_xq(h) -> bf16 (MFMA); also emits h_bf (fused f32->bf16)
    node_mlp_mfma_kernel<128, unsigned short><<<dim3((N + 127) / 128), dim3(256), 0, stream>>>(
        nullptr, h, nullptr, nullptr, h_bf,
        W1q, W2q, P[13], P[14], P[15], P[17], q_bf, N);

    // per-edge fused k/v MLPs (MFMA) + scores + exp + den + pk-bf16 scatter
    kv_mfma_kernel<<<dim3((E + 63) / 64), dim3(256), 0, stream>>>(
        h_bf, q_bf, r_feat, edge_feat, e_w, src, dst, B1p, B2p,
        P[1], P[7], P[2], P[3], P[8], P[9], P[5], P[11],
        attn_bf, den, E);

    // final = MLP_out([attn/den | h])   (MFMA, normalization in staging)
    node_mlp_mfma_kernel<256, float><<<dim3((N + 127) / 128), dim3(256), 0, stream>>>(
        h_bf, nullptr, attn_bf, den, nullptr,
        W1o, W2o, P[19], P[20], P[21], P[23], (float*)d_out, N);
}